// Round 5
// baseline (80541.766 us; speedup 1.0000x reference)
//
#include <hip/hip_runtime.h>
#include <hip/hip_bf16.h>
#include <cstdint>
#include <cstddef>

namespace {

constexpr int S_LEN  = 256;
constexpr int BATCH  = 256;
constexpr int NH     = 512;
constexpr int NE     = 256;
constexpr int NSTEPS = 127;          // TGT_LEN-1
constexpr int N1     = 2048;         // [Wo;Wz;Wr;Wn_partial]
constexpr size_t SB        = (size_t)S_LEN * BATCH;   // 65536
constexpr size_t SRC_ELEMS = SB * NH;                 // 33,554,432
constexpr int FLAG_INTS = NSTEPS * (3 * 256 + 1);     // fS,fQ,fP per b + fC

typedef __attribute__((ext_vector_type(8))) short  short8v;
typedef __attribute__((ext_vector_type(4))) float  float4v;
typedef unsigned short us;

constexpr int EPI_EPROJ = 1, EPI_S0 = 4;

__device__ __forceinline__ float bf2f(us u) {
  union { unsigned int i; float f; } c; c.i = ((unsigned int)u) << 16; return c.f;
}
__device__ __forceinline__ us f2bf(float f) {
  union { float f; unsigned int i; } c; c.f = f;
  unsigned int x = c.i;
  return (us)((x + 0x7FFFu + ((x >> 16) & 1u)) >> 16);
}
// tanh(x) = 1 - 2/(e^{2x}+1)
__device__ __forceinline__ float tanh2(float x) {
  return 1.f - 2.f * __builtin_amdgcn_rcpf(__expf(2.f * x) + 1.f);
}
__device__ __forceinline__ float sigm(float x) {
  return __builtin_amdgcn_rcpf(1.f + __expf(-x));
}
__device__ __forceinline__ void flag_add(int* p) {
  __hip_atomic_fetch_add(p, 1, __ATOMIC_RELEASE, __HIP_MEMORY_SCOPE_AGENT);
}
__device__ __forceinline__ void flag_wait(int* p, int target) {
  while (__hip_atomic_load(p, __ATOMIC_ACQUIRE, __HIP_MEMORY_SCOPE_AGENT) < target)
    __builtin_amdgcn_s_sleep(8);
}

// ---------------- prologue: conversions ----------------

// src_enc (S,B,H) f32 -> src_t (B,S,H) bf16
__global__ void k_conv_src(const float* __restrict__ src, us* __restrict__ dst) {
  const int total = S_LEN * BATCH * 64;       // 8-elem chunks, dest-linear
  int i = blockIdx.x * blockDim.x + threadIdx.x;
  int stride = gridDim.x * blockDim.x;
  for (; i < total; i += stride) {
    int c = i & 63, s = (i >> 6) & 255, b = i >> 14;
    const float* p = src + ((size_t)s * BATCH + b) * NH + c * 8;
    float4 v0 = *(const float4*)p;
    float4 v1 = *(const float4*)(p + 4);
    us o[8] = { f2bf(v0.x), f2bf(v0.y), f2bf(v0.z), f2bf(v0.w),
                f2bf(v1.x), f2bf(v1.y), f2bf(v1.z), f2bf(v1.w) };
    *(short8v*)(dst + (size_t)i * 8) = *(const short8v*)o;
  }
}

__global__ void k_conv_w(const float* __restrict__ Wo, const float* __restrict__ Wz,
                         const float* __restrict__ Wr, const float* __restrict__ Wn,
                         const float* __restrict__ Wa, const float* __restrict__ Ws,
                         const float* __restrict__ Wob, const float* __restrict__ Wzb,
                         const float* __restrict__ Wrb, const float* __restrict__ Wnb,
                         us* __restrict__ W1cat, us* __restrict__ Wns,
                         us* __restrict__ Was, us* __restrict__ Wae,
                         us* __restrict__ Wsbf, float* __restrict__ bcat) {
  const int T1 = 2048 * 1280;
  const int T2 = 512 * 512;
  const int total = T1 + 4 * T2 + 2048;
  int i = blockIdx.x * blockDim.x + threadIdx.x;
  int stride = gridDim.x * blockDim.x;
  for (; i < total; i += stride) {
    int idx = i;
    if (idx < T1) {
      int row = idx / 1280, col = idx - row * 1280;
      float v;
      if      (row < 512)  v = Wo[row * 1280 + col];
      else if (row < 1024) v = Wz[(row - 512) * 1280 + col];
      else if (row < 1536) v = Wr[(row - 1024) * 1280 + col];
      else {
        int g = row - 1536;
        v = (col >= 256 && col < 768) ? 0.f : Wn[g * 1280 + col];
      }
      W1cat[idx] = f2bf(v);
    } else if ((idx -= T1) < T2) {
      int g = idx >> 9, j = idx & 511;
      Wns[idx] = f2bf(Wn[g * 1280 + 256 + j]);
    } else if ((idx -= T2) < T2) {
      int g = idx >> 9, h = idx & 511;
      Was[idx] = f2bf(Wa[g * 1024 + h]);
    } else if ((idx -= T2) < T2) {
      int g = idx >> 9, h = idx & 511;
      Wae[idx] = f2bf(Wa[g * 1024 + 512 + h]);
    } else if ((idx -= T2) < T2) {
      Wsbf[idx] = f2bf(Ws[idx]);
    } else {
      idx -= T2;
      bcat[idx] = (idx < 512) ? Wob[idx]
                : (idx < 1024) ? Wzb[idx - 512]
                : (idx < 1536) ? Wrb[idx - 1024]
                               : Wnb[idx - 1536];
    }
  }
}

__global__ void k_emb(const int* __restrict__ tgt, const float* __restrict__ table,
                      us* __restrict__ emb) {
  const int total = NSTEPS * BATCH * NE;
  int i = blockIdx.x * blockDim.x + threadIdx.x;
  int stride = gridDim.x * blockDim.x;
  for (; i < total; i += stride) {
    int e  = i & (NE - 1);
    int tb = i >> 8;
    int sym = tgt[tb];
    emb[i] = f2bf(table[sym * NE + e]);
  }
}

// ------------- prologue 8-wave MFMA GEMM tile: 64x128, BK=64 (s0 / eproj) ----------
template<int EPI>
__global__ __launch_bounds__(512, 2) void k_gemm(
    const us* __restrict__ A0, int lda, const us* __restrict__ Bw, int ldb, int K,
    const float* __restrict__ bias, float* __restrict__ f0, us* __restrict__ g0) {
  __shared__ alignas(16) char smem[49152];
  char* As0 = smem;               // 2 x 8192
  char* Bs0 = smem + 16384;       // 2 x 16384
  const int tid = threadIdx.x;
  const int m0 = blockIdx.x * 64, n0 = blockIdx.y * 128;
  const int arow = tid >> 3, ac = (tid & 7) * 8;
  const int brow = tid >> 2, bc = (tid & 3) * 16;
  short8v ar, br0, br1;

  auto loadT = [&](int k0) {
    ar = *(const short8v*)(A0 + (size_t)(m0 + arow) * lda + (k0 + ac));
    const us* q = Bw + (size_t)(n0 + brow) * ldb + (k0 + bc);
    br0 = *(const short8v*)q;
    br1 = *(const short8v*)(q + 8);
  };
  auto stage = [&](int buf) {
    *(short8v*)(As0 + buf * 8192 + arow * 128 + ((ac * 2) ^ ((arow & 7) << 4))) = ar;
    char* bb = Bs0 + buf * 16384 + brow * 128;
    const int sw = (brow & 7) << 4;
    *(short8v*)(bb + ((bc * 2) ^ sw)) = br0;
    *(short8v*)(bb + ((bc * 2 + 16) ^ sw)) = br1;
  };

  const int lane = tid & 63, wave = tid >> 6;
  const int wm = (wave >> 2) * 32, wn = (wave & 3) * 32;
  const int fr = lane & 15, kq = lane >> 4;
  const int ra0 = wm + fr, ra1 = ra0 + 16;
  const int rb0 = wn + fr, rb1 = rb0 + 16;
  float4v acc00 = {0,0,0,0}, acc01 = {0,0,0,0}, acc10 = {0,0,0,0}, acc11 = {0,0,0,0};

  loadT(0);
  stage(0);
  const int nit = K >> 6;
  for (int it = 0; it < nit; ++it) {
    __syncthreads();
    if (it + 1 < nit) loadT((it + 1) << 6);
    const char* ab = As0 + (it & 1) * 8192;
    const char* bb = Bs0 + (it & 1) * 16384;
    #pragma unroll
    for (int ks = 0; ks < 2; ++ks) {
      const int cb = ks * 64 + kq * 16;
      short8v a0 = *(const short8v*)(ab + ra0 * 128 + (cb ^ ((ra0 & 7) << 4)));
      short8v a1 = *(const short8v*)(ab + ra1 * 128 + (cb ^ ((ra1 & 7) << 4)));
      short8v b0 = *(const short8v*)(bb + rb0 * 128 + (cb ^ ((rb0 & 7) << 4)));
      short8v b1 = *(const short8v*)(bb + rb1 * 128 + (cb ^ ((rb1 & 7) << 4)));
      acc00 = __builtin_amdgcn_mfma_f32_16x16x32_bf16(a0, b0, acc00, 0, 0, 0);
      acc01 = __builtin_amdgcn_mfma_f32_16x16x32_bf16(a0, b1, acc01, 0, 0, 0);
      acc10 = __builtin_amdgcn_mfma_f32_16x16x32_bf16(a1, b0, acc10, 0, 0, 0);
      acc11 = __builtin_amdgcn_mfma_f32_16x16x32_bf16(a1, b1, acc11, 0, 0, 0);
    }
    if (it + 1 < nit) stage((it + 1) & 1);
  }

  #pragma unroll
  for (int am = 0; am < 2; ++am) {
    #pragma unroll
    for (int bn = 0; bn < 2; ++bn) {
      float4v a = am ? (bn ? acc11 : acc10) : (bn ? acc01 : acc00);
      #pragma unroll
      for (int r = 0; r < 4; ++r) {
        const int rowO = m0 + wm + am * 16 + kq * 4 + r;
        const int colO = n0 + wn + bn * 16 + fr;
        float v = a[r];
        if (EPI == EPI_S0) {
          float tv = tanh2(v + bias[colO]);
          f0[(size_t)rowO * 512 + colO] = tv;
          g0[(size_t)rowO * 512 + colO] = f2bf(tv);
        } else { // EPI_EPROJ
          g0[(size_t)rowO * 512 + colO] = f2bf(v + bias[colO]);
        }
      }
    }
  }
}

// ---------------- the per-step mega kernel ----------------
struct SA {
  const us *ep, *src, *Was, *Wns, *W1cat, *emb;
  const float *bcat, *vaw; const int *slen;
  float *s_f32; us *s_bf; float *qbuf;
  float *zi, *npart; us *xn, *ci;
  float *pbuf, *cpart, *mlbuf;
  float *dec_out, *dec_st, *dec_at;
  int *flags;
  int t;
};

__global__ __launch_bounds__(256, 4) void k_step(SA a) {
  __shared__ alignas(16) char smem[24576];
  const int bid = blockIdx.x, tid = threadIdx.x;
  const int b = bid >> 2, c = bid & 3;
  const int lane = tid & 63, wv = tid >> 6;      // 4 waves
  const int g0l = lane * 8;
  const int t = a.t;
  const int has_gru = (t > 0);
  int* fS = a.flags + t * 256;
  int* fQ = a.flags + NSTEPS * 256 + t * 256;
  int* fP = a.flags + 2 * NSTEPS * 256 + t * 256;
  int* fC = a.flags + 3 * NSTEPS * 256 + t;
  const us* emb_t    = a.emb    + (size_t)t * BATCH * NE;
  float*    dec_out_t = a.dec_out + (size_t)t * BATCH * NH;
  float*    dec_st_t  = a.dec_st  + (size_t)t * BATCH * NH;
  float*    dec_at_t  = a.dec_at  + (size_t)t * BATCH * S_LEN;

  // ======== P0: GRU finish of step t-1 -> s_t ; dec_states[t] ========
  {
    const int h = c * 128 + (tid >> 1), half = tid & 1;
    float s_new;
    if (has_gru) {
      float* xnf = (float*)smem;
      xnf[tid]       = bf2f(a.xn[b * 512 + tid]);
      xnf[tid + 256] = bf2f(a.xn[b * 512 + tid + 256]);
      __syncthreads();
      const us* wr = a.Wns + (size_t)h * 512 + half * 256;
      float acc = 0.f;
      #pragma unroll
      for (int i = 0; i < 32; i++) {
        short8v w8 = ((const short8v*)wr)[i];
        #pragma unroll
        for (int j = 0; j < 8; j++)
          acc = __builtin_fmaf(bf2f((us)w8[j]), xnf[half * 256 + i * 8 + j], acc);
      }
      acc += __shfl_xor(acc, 1, 64);
      float z  = a.zi[b * 512 + h];
      float so = a.s_f32[b * 512 + h];
      float nv = tanh2(a.npart[b * 512 + h] + acc);
      s_new = (1.f - z) * so + z * nv;
      if (half == 0) {
        a.s_f32[b * 512 + h] = s_new;
        a.s_bf[b * 512 + h]  = f2bf(s_new);
      }
    } else {
      s_new = a.s_f32[b * 512 + h];
    }
    if (half == 0) __builtin_nontemporal_store(s_new, &dec_st_t[b * 512 + h]);
    __threadfence();
    __syncthreads();
    if (tid == 0) flag_add(&fS[b]);
  }

  // ======== P1: q-quarter = 2 * (s_t @ Was^T) ========
  {
    if (tid == 0) flag_wait(&fS[b], 4);
    __syncthreads();
    float* sfl = (float*)smem;
    sfl[tid]       = a.s_f32[b * 512 + tid];
    sfl[tid + 256] = a.s_f32[b * 512 + tid + 256];
    __syncthreads();
    const int h = c * 128 + (tid >> 1), half = tid & 1;
    const us* wr = a.Was + (size_t)h * 512 + half * 256;
    float acc = 0.f;
    #pragma unroll
    for (int i = 0; i < 32; i++) {
      short8v w8 = ((const short8v*)wr)[i];
      #pragma unroll
      for (int j = 0; j < 8; j++)
        acc = __builtin_fmaf(bf2f((us)w8[j]), sfl[half * 256 + i * 8 + j], acc);
    }
    acc += __shfl_xor(acc, 1, 64);
    if (half == 0) a.qbuf[b * 512 + h] = 2.f * acc;
    __threadfence();
    __syncthreads();
    if (tid == 0) flag_add(&fQ[b]);
  }

  // ======== P2: chunk scores + chunk softmax + ci partials ========
  {
    if (tid == 0) flag_wait(&fQ[b], 4);
    __syncthreads();
    float* eich  = (float*)smem;          // 64
    float* pch   = eich + 64;             // 64
    float* wpart = (float*)(smem + 1024); // [4][512]

    float vv2[8]; float sumv = 0.f;
    {
      const float* vp = a.vaw + g0l;
      #pragma unroll
      for (int j = 0; j < 8; j++) { vv2[j] = 2.f * vp[j]; sumv += vp[j]; }
      #pragma unroll
      for (int off = 32; off > 0; off >>= 1) sumv += __shfl_xor(sumv, off, 64);
    }
    float q2[8];
    {
      const float* qp = a.qbuf + b * 512 + g0l;
      #pragma unroll
      for (int j = 0; j < 8; j++) q2[j] = qp[j];
    }
    const int len = a.slen[b];

    // scores over this chunk's 64 s-rows (wave wv handles wv+4i)
    {
      const us* epb = a.ep + ((size_t)b * S_LEN + c * 64 + wv) * NH + g0l;
      short8v cur = *(const short8v*)epb;
      #pragma unroll
      for (int i = 0; i < 16; ++i) {
        short8v nxt;
        if (i < 15) nxt = *(const short8v*)(epb + (size_t)(i + 1) * 4 * NH);
        float acc = 0.f;
        #pragma unroll
        for (int j = 0; j < 8; j++) {
          float arg = __builtin_fmaf(bf2f((us)cur[j]), 2.f, q2[j]);
          acc = __builtin_fmaf(vv2[j],
                __builtin_amdgcn_rcpf(__expf(arg) + 1.f), acc);
        }
        #pragma unroll
        for (int off = 32; off > 0; off >>= 1) acc += __shfl_xor(acc, off, 64);
        if (lane == 0) {
          int sg = c * 64 + wv + 4 * i;
          eich[wv + 4 * i] = (sg < len) ? (sumv - acc) : -3.0e38f;
        }
        if (i < 15) cur = nxt;
      }
    }
    __syncthreads();

    // chunk softmax (wave 0)
    if (wv == 0) {
      float e = eich[lane];
      float m = e;
      #pragma unroll
      for (int off = 32; off > 0; off >>= 1) m = fmaxf(m, __shfl_xor(m, off, 64));
      float p = __expf(e - m);
      float l = p;
      #pragma unroll
      for (int off = 32; off > 0; off >>= 1) l += __shfl_xor(l, off, 64);
      pch[lane] = p;
      a.pbuf[b * 256 + c * 64 + lane] = p;
      if (lane == 0) {
        a.mlbuf[(b * 4 + c) * 2]     = m;
        a.mlbuf[(b * 4 + c) * 2 + 1] = l;
      }
    }
    __syncthreads();

    // ci partials: c~[h] = sum_s p[s]*src[b,s,h]
    {
      float a8[8] = {0,0,0,0,0,0,0,0};
      const us* sb = a.src + ((size_t)b * S_LEN + c * 64 + wv) * NH + g0l;
      short8v cur = *(const short8v*)sb;
      #pragma unroll
      for (int i = 0; i < 16; ++i) {
        short8v nxt;
        if (i < 15) nxt = *(const short8v*)(sb + (size_t)(i + 1) * 4 * NH);
        float pv = pch[wv + 4 * i];
        #pragma unroll
        for (int j = 0; j < 8; j++)
          a8[j] = __builtin_fmaf(pv, bf2f((us)cur[j]), a8[j]);
        if (i < 15) cur = nxt;
      }
      #pragma unroll
      for (int j = 0; j < 8; j++) wpart[wv * 512 + g0l + j] = a8[j];
    }
    __syncthreads();
    #pragma unroll
    for (int rep = 0; rep < 2; rep++) {
      int hh = tid + rep * 256;
      float cp = wpart[hh] + wpart[512 + hh] + wpart[1024 + hh] + wpart[1536 + hh];
      a.cpart[((size_t)b * 4 + c) * 512 + hh] = cp;
    }
    __threadfence();
    __syncthreads();
    if (tid == 0) flag_add(&fP[b]);
  }

  // ======== P3: combine (c==0 blocks) -> ci, dec_attns[t] ========
  if (c == 0) {
    if (tid == 0) flag_wait(&fP[b], 4);
    __syncthreads();
    float mm[4], ll[4], m = -3.0e38f;
    #pragma unroll
    for (int cc = 0; cc < 4; cc++) {
      mm[cc] = a.mlbuf[(b * 4 + cc) * 2];
      ll[cc] = a.mlbuf[(b * 4 + cc) * 2 + 1];
      m = fmaxf(m, mm[cc]);
    }
    float wgt[4], l = 0.f;
    #pragma unroll
    for (int cc = 0; cc < 4; cc++) { wgt[cc] = __expf(mm[cc] - m); l += wgt[cc] * ll[cc]; }
    float invl = __builtin_amdgcn_rcpf(l);
    #pragma unroll
    for (int rep = 0; rep < 2; rep++) {
      int hh = tid + rep * 256;
      float s = wgt[0] * a.cpart[((size_t)b * 4 + 0) * 512 + hh]
              + wgt[1] * a.cpart[((size_t)b * 4 + 1) * 512 + hh]
              + wgt[2] * a.cpart[((size_t)b * 4 + 2) * 512 + hh]
              + wgt[3] * a.cpart[((size_t)b * 4 + 3) * 512 + hh];
      a.ci[b * 512 + hh] = f2bf(s * invl);
    }
    float ai = a.pbuf[b * 256 + tid] * wgt[tid >> 6] * invl;
    __builtin_nontemporal_store(ai, &dec_at_t[b * 256 + tid]);
    __threadfence();
    __syncthreads();
    if (tid == 0) flag_add(fC);
  }

  // ======== P4: STEP1 GEMM (blocks 0..63), 64x128 tile, K=1280 ========
  if (bid < 64) {
    if (tid == 0) flag_wait(fC, 256);
    __syncthreads();
    char* As = smem;            // 64 x 128B
    char* Bs = smem + 8192;     // 128 x 128B
    const int m0 = (bid >> 4) * 64, n0 = (bid & 15) * 128;
    const int fr = lane & 15, kq = lane >> 4;
    const int wm = (wv & 1) * 32, wn0 = (wv >> 1) * 32;
    const int ra0 = wm + fr, ra1 = ra0 + 16;
    float4v acc[2][2][2];
    #pragma unroll
    for (int x = 0; x < 2; x++)
      #pragma unroll
      for (int y = 0; y < 2; y++)
        #pragma unroll
        for (int z = 0; z < 2; z++) acc[x][y][z] = (float4v){0,0,0,0};

    for (int kt = 0; kt < 20; ++kt) {
      __syncthreads();
      #pragma unroll
      for (int j = 0; j < 2; j++) {
        int cid = tid + 256 * j;
        int arow = cid >> 3, ac8 = (cid & 7) * 8;
        int cc = kt * 64 + ac8, rowg = m0 + arow;
        const us* p = (cc < 256) ? emb_t + (size_t)rowg * 256 + cc
                    : (cc < 768) ? a.s_bf + (size_t)rowg * 512 + (cc - 256)
                                 : (const us*)a.ci + (size_t)rowg * 512 + (cc - 768);
        *(short8v*)(As + arow * 128 + ((ac8 * 2) ^ ((arow & 7) << 4))) =
            *(const short8v*)p;
      }
      #pragma unroll
      for (int j = 0; j < 4; j++) {
        int cid = tid + 256 * j;
        int brow = cid >> 3, bc8 = (cid & 7) * 8;
        *(short8v*)(Bs + brow * 128 + ((bc8 * 2) ^ ((brow & 7) << 4))) =
            *(const short8v*)(a.W1cat + (size_t)(n0 + brow) * 1280 + kt * 64 + bc8);
      }
      __syncthreads();
      #pragma unroll
      for (int ks = 0; ks < 2; ++ks) {
        const int cb = ks * 64 + kq * 16;
        short8v a0 = *(const short8v*)(As + ra0 * 128 + (cb ^ ((ra0 & 7) << 4)));
        short8v a1 = *(const short8v*)(As + ra1 * 128 + (cb ^ ((ra1 & 7) << 4)));
        #pragma unroll
        for (int nh = 0; nh < 2; ++nh) {
          const int rb0 = wn0 + nh * 64 + fr, rb1 = rb0 + 16;
          short8v b0 = *(const short8v*)(Bs + rb0 * 128 + (cb ^ ((rb0 & 7) << 4)));
          short8v b1 = *(const short8v*)(Bs + rb1 * 128 + (cb ^ ((rb1 & 7) << 4)));
          acc[nh][0][0] = __builtin_amdgcn_mfma_f32_16x16x32_bf16(a0, b0, acc[nh][0][0], 0, 0, 0);
          acc[nh][0][1] = __builtin_amdgcn_mfma_f32_16x16x32_bf16(a0, b1, acc[nh][0][1], 0, 0, 0);
          acc[nh][1][0] = __builtin_amdgcn_mfma_f32_16x16x32_bf16(a1, b0, acc[nh][1][0], 0, 0, 0);
          acc[nh][1][1] = __builtin_amdgcn_mfma_f32_16x16x32_bf16(a1, b1, acc[nh][1][1], 0, 0, 0);
        }
      }
    }

    #pragma unroll
    for (int nh = 0; nh < 2; ++nh) {
      #pragma unroll
      for (int am = 0; am < 2; ++am) {
        #pragma unroll
        for (int bn = 0; bn < 2; ++bn) {
          #pragma unroll
          for (int r = 0; r < 4; ++r) {
            const int rowO = m0 + wm + am * 16 + kq * 4 + r;
            const int colO = n0 + wn0 + nh * 64 + bn * 16 + fr;
            float v = acc[nh][am][bn][r] + a.bcat[colO];
            const int qd = colO >> 9, j = colO & 511;
            const size_t idx = (size_t)rowO * 512 + j;
            if      (qd == 0) __builtin_nontemporal_store(v, &dec_out_t[idx]);
            else if (qd == 1) a.zi[idx] = sigm(v);
            else if (qd == 2) a.xn[idx] = f2bf(sigm(v) * a.s_f32[idx]);
            else              a.npart[idx] = v;
          }
        }
      }
    }
  }
}

} // namespace

extern "C" void kernel_launch(void* const* d_in, const int* in_sizes, int n_in,
                              void* d_out, int out_size, void* d_ws, size_t ws_size,
                              hipStream_t stream) {
  const float* src_enc  = (const float*)d_in[0];
  const int*   tgt      = (const int*)d_in[1];
  const int*   slen     = (const int*)d_in[2];
  const float* emb_tab  = (const float*)d_in[3];
  const float* Wsw      = (const float*)d_in[4];
  const float* Wsb      = (const float*)d_in[5];
  const float* Wzw      = (const float*)d_in[6];
  const float* Wzb      = (const float*)d_in[7];
  const float* Wrw      = (const float*)d_in[8];
  const float* Wrb      = (const float*)d_in[9];
  const float* Wnw      = (const float*)d_in[10];
  const float* Wnb      = (const float*)d_in[11];
  const float* Waw      = (const float*)d_in[12];
  const float* Wab      = (const float*)d_in[13];
  const float* vaw      = (const float*)d_in[14];
  const float* Wow      = (const float*)d_in[15];
  const float* Wob      = (const float*)d_in[16];

  char* ws = (char*)d_ws;
  size_t off = 0;
  auto alloc = [&](size_t bytes) -> void* {
    void* p = ws + off;
    off = (off + bytes + 255) & ~(size_t)255;
    return p;
  };
  us*    src_t  = (us*)alloc(SRC_ELEMS * 2);
  us*    ep_t   = (us*)alloc(SRC_ELEMS * 2);
  us*    emb_bf = (us*)alloc((size_t)NSTEPS * BATCH * NE * 2);
  us*    W1cat  = (us*)alloc((size_t)N1 * 1280 * 2);
  us*    Wns    = (us*)alloc((size_t)512 * 512 * 2);
  us*    Was    = (us*)alloc((size_t)512 * 512 * 2);
  us*    Wae    = (us*)alloc((size_t)512 * 512 * 2);
  us*    Wsbf   = (us*)alloc((size_t)512 * 512 * 2);
  float* bcat   = (float*)alloc((size_t)N1 * 4);
  float* s_f32  = (float*)alloc((size_t)BATCH * NH * 4);
  us*    s_bf   = (us*)alloc((size_t)BATCH * NH * 2);
  float* qbuf   = (float*)alloc((size_t)BATCH * NH * 4);
  float* zi     = (float*)alloc((size_t)BATCH * NH * 4);
  float* npart  = (float*)alloc((size_t)BATCH * NH * 4);
  us*    xn_bf  = (us*)alloc((size_t)BATCH * NH * 2);
  us*    ci_bf  = (us*)alloc((size_t)BATCH * NH * 2);
  float* pbuf   = (float*)alloc((size_t)BATCH * S_LEN * 4);
  float* cpart  = (float*)alloc((size_t)BATCH * 4 * NH * 4);
  float* mlbuf  = (float*)alloc((size_t)BATCH * 4 * 2 * 4);
  int*   flags  = (int*)alloc((size_t)FLAG_INTS * 4);

  float* out         = (float*)d_out;
  float* dec_outputs = out;
  float* dec_states  = out + (size_t)NSTEPS * BATCH * NH;
  float* dec_attns   = dec_states + (size_t)NSTEPS * BATCH * NH;

  hipMemsetAsync(flags, 0, (size_t)FLAG_INTS * 4, stream);

  // ---- prologue ----
  k_conv_src<<<4096, 256, 0, stream>>>(src_enc, src_t);
  k_conv_w<<<2048, 256, 0, stream>>>(Wow, Wzw, Wrw, Wnw, Waw, Wsw,
                                     Wob, Wzb, Wrb, Wnb,
                                     W1cat, Wns, Was, Wae, Wsbf, bcat);
  k_emb<<<2048, 256, 0, stream>>>(tgt, emb_tab, emb_bf);
  // s0 = tanh(src_enc[0] @ Ws^T + Ws_b): src_t rows (b, s=0) at stride S*NH
  k_gemm<EPI_S0><<<dim3(4, 4), 512, 0, stream>>>(
      src_t, S_LEN * NH, Wsbf, 512, 512, Wsb, s_f32, s_bf);
  // ep_t[b,s] = src_t[b,s] @ Wae^T + Wa_b
  k_gemm<EPI_EPROJ><<<dim3(1024, 4), 512, 0, stream>>>(
      src_t, 512, Wae, 512, 512, Wab, nullptr, ep_t);

  // ---- 127 steps x 1 kernel ----
  SA a;
  a.ep = ep_t; a.src = src_t; a.Was = Was; a.Wns = Wns; a.W1cat = W1cat;
  a.emb = emb_bf; a.bcat = bcat; a.vaw = vaw; a.slen = slen;
  a.s_f32 = s_f32; a.s_bf = s_bf; a.qbuf = qbuf;
  a.zi = zi; a.npart = npart; a.xn = xn_bf; a.ci = ci_bf;
  a.pbuf = pbuf; a.cpart = cpart; a.mlbuf = mlbuf;
  a.dec_out = dec_outputs; a.dec_st = dec_states; a.dec_at = dec_attns;
  a.flags = flags;
  for (int t = 0; t < NSTEPS; t++) {
    a.t = t;
    k_step<<<1024, 256, 0, stream>>>(a);
  }
}

// Round 6
// 14213.962 us; speedup vs baseline: 5.6664x; 5.6664x over previous
//
#include <hip/hip_runtime.h>
#include <hip/hip_bf16.h>
#include <cstdint>
#include <cstddef>

namespace {

constexpr int S_LEN  = 256;
constexpr int BATCH  = 256;
constexpr int NH     = 512;
constexpr int NE     = 256;
constexpr int NSTEPS = 127;          // TGT_LEN-1
constexpr int N1     = 2048;         // [Wo;Wz;Wr;Wn_partial]
constexpr size_t SB        = (size_t)S_LEN * BATCH;   // 65536
constexpr size_t SRC_ELEMS = SB * NH;                 // 33,554,432

typedef __attribute__((ext_vector_type(8))) short  short8v;
typedef __attribute__((ext_vector_type(4))) float  float4v;
typedef unsigned short us;

constexpr int EPI_EPROJ = 1, EPI_S0 = 4;

__device__ __forceinline__ float bf2f(us u) {
  union { unsigned int i; float f; } c; c.i = ((unsigned int)u) << 16; return c.f;
}
__device__ __forceinline__ us f2bf(float f) {
  union { float f; unsigned int i; } c; c.f = f;
  unsigned int x = c.i;
  return (us)((x + 0x7FFFu + ((x >> 16) & 1u)) >> 16);
}
// tanh(x) = 1 - 2/(e^{2x}+1)
__device__ __forceinline__ float tanh2(float x) {
  return 1.f - 2.f * __builtin_amdgcn_rcpf(__expf(2.f * x) + 1.f);
}
__device__ __forceinline__ float sigm(float x) {
  return __builtin_amdgcn_rcpf(1.f + __expf(-x));
}
// one wave stages 1KB: per-lane global addr g (lane*16B apart), uniform LDS dst l
__device__ __forceinline__ void gload16(const us* g, us* l) {
  __builtin_amdgcn_global_load_lds(
      (const __attribute__((address_space(1))) unsigned int*)g,
      (__attribute__((address_space(3))) unsigned int*)l, 16, 0, 0);
}

// ---------------- prologue: conversions ----------------

// src_enc (S,B,H) f32 -> src_t (B,S,H) bf16
__global__ void k_conv_src(const float* __restrict__ src, us* __restrict__ dst) {
  const int total = S_LEN * BATCH * 64;       // 8-elem chunks, dest-linear
  int i = blockIdx.x * blockDim.x + threadIdx.x;
  int stride = gridDim.x * blockDim.x;
  for (; i < total; i += stride) {
    int c = i & 63, s = (i >> 6) & 255, b = i >> 14;
    const float* p = src + ((size_t)s * BATCH + b) * NH + c * 8;
    float4 v0 = *(const float4*)p;
    float4 v1 = *(const float4*)(p + 4);
    us o[8] = { f2bf(v0.x), f2bf(v0.y), f2bf(v0.z), f2bf(v0.w),
                f2bf(v1.x), f2bf(v1.y), f2bf(v1.z), f2bf(v1.w) };
    *(short8v*)(dst + (size_t)i * 8) = *(const short8v*)o;
  }
}

__global__ void k_conv_w(const float* __restrict__ Wo, const float* __restrict__ Wz,
                         const float* __restrict__ Wr, const float* __restrict__ Wn,
                         const float* __restrict__ Wa, const float* __restrict__ Ws,
                         const float* __restrict__ Wob, const float* __restrict__ Wzb,
                         const float* __restrict__ Wrb, const float* __restrict__ Wnb,
                         us* __restrict__ W1cat, us* __restrict__ Wns,
                         us* __restrict__ Was, us* __restrict__ Wae,
                         us* __restrict__ Wsbf, float* __restrict__ bcat) {
  const int T1 = 2048 * 1280;
  const int T2 = 512 * 512;
  const int total = T1 + 4 * T2 + 2048;
  int i = blockIdx.x * blockDim.x + threadIdx.x;
  int stride = gridDim.x * blockDim.x;
  for (; i < total; i += stride) {
    int idx = i;
    if (idx < T1) {
      int row = idx / 1280, col = idx - row * 1280;
      float v;
      if      (row < 512)  v = Wo[row * 1280 + col];
      else if (row < 1024) v = Wz[(row - 512) * 1280 + col];
      else if (row < 1536) v = Wr[(row - 1024) * 1280 + col];
      else {
        int g = row - 1536;
        v = (col >= 256 && col < 768) ? 0.f : Wn[g * 1280 + col];
      }
      W1cat[idx] = f2bf(v);
    } else if ((idx -= T1) < T2) {
      int g = idx >> 9, j = idx & 511;
      Wns[idx] = f2bf(Wn[g * 1280 + 256 + j]);
    } else if ((idx -= T2) < T2) {
      int g = idx >> 9, h = idx & 511;
      Was[idx] = f2bf(Wa[g * 1024 + h]);
    } else if ((idx -= T2) < T2) {
      int g = idx >> 9, h = idx & 511;
      Wae[idx] = f2bf(Wa[g * 1024 + 512 + h]);
    } else if ((idx -= T2) < T2) {
      Wsbf[idx] = f2bf(Ws[idx]);
    } else {
      idx -= T2;
      bcat[idx] = (idx < 512) ? Wob[idx]
                : (idx < 1024) ? Wzb[idx - 512]
                : (idx < 1536) ? Wrb[idx - 1024]
                               : Wnb[idx - 1536];
    }
  }
}

__global__ void k_emb(const int* __restrict__ tgt, const float* __restrict__ table,
                      us* __restrict__ emb) {
  const int total = NSTEPS * BATCH * NE;
  int i = blockIdx.x * blockDim.x + threadIdx.x;
  int stride = gridDim.x * blockDim.x;
  for (; i < total; i += stride) {
    int e  = i & (NE - 1);
    int tb = i >> 8;
    int sym = tgt[tb];
    emb[i] = f2bf(table[sym * NE + e]);
  }
}

// ------------- prologue 8-wave MFMA GEMM tile: 64x128, BK=64 (s0 / eproj) ----------
template<int EPI>
__global__ __launch_bounds__(512, 2) void k_gemm(
    const us* __restrict__ A0, int lda, const us* __restrict__ Bw, int ldb, int K,
    const float* __restrict__ bias, float* __restrict__ f0, us* __restrict__ g0) {
  __shared__ alignas(16) char smem[49152];
  char* As0 = smem;               // 2 x 8192
  char* Bs0 = smem + 16384;       // 2 x 16384
  const int tid = threadIdx.x;
  const int m0 = blockIdx.x * 64, n0 = blockIdx.y * 128;
  const int arow = tid >> 3, ac = (tid & 7) * 8;
  const int brow = tid >> 2, bc = (tid & 3) * 16;
  short8v ar, br0, br1;

  auto loadT = [&](int k0) {
    ar = *(const short8v*)(A0 + (size_t)(m0 + arow) * lda + (k0 + ac));
    const us* q = Bw + (size_t)(n0 + brow) * ldb + (k0 + bc);
    br0 = *(const short8v*)q;
    br1 = *(const short8v*)(q + 8);
  };
  auto stage = [&](int buf) {
    *(short8v*)(As0 + buf * 8192 + arow * 128 + ((ac * 2) ^ ((arow & 7) << 4))) = ar;
    char* bb = Bs0 + buf * 16384 + brow * 128;
    const int sw = (brow & 7) << 4;
    *(short8v*)(bb + ((bc * 2) ^ sw)) = br0;
    *(short8v*)(bb + ((bc * 2 + 16) ^ sw)) = br1;
  };

  const int lane = tid & 63, wave = tid >> 6;
  const int wm = (wave >> 2) * 32, wn = (wave & 3) * 32;
  const int fr = lane & 15, kq = lane >> 4;
  const int ra0 = wm + fr, ra1 = ra0 + 16;
  const int rb0 = wn + fr, rb1 = rb0 + 16;
  float4v acc00 = {0,0,0,0}, acc01 = {0,0,0,0}, acc10 = {0,0,0,0}, acc11 = {0,0,0,0};

  loadT(0);
  stage(0);
  const int nit = K >> 6;
  for (int it = 0; it < nit; ++it) {
    __syncthreads();
    if (it + 1 < nit) loadT((it + 1) << 6);
    const char* ab = As0 + (it & 1) * 8192;
    const char* bb = Bs0 + (it & 1) * 16384;
    #pragma unroll
    for (int ks = 0; ks < 2; ++ks) {
      const int cb = ks * 64 + kq * 16;
      short8v a0 = *(const short8v*)(ab + ra0 * 128 + (cb ^ ((ra0 & 7) << 4)));
      short8v a1 = *(const short8v*)(ab + ra1 * 128 + (cb ^ ((ra1 & 7) << 4)));
      short8v b0 = *(const short8v*)(bb + rb0 * 128 + (cb ^ ((rb0 & 7) << 4)));
      short8v b1 = *(const short8v*)(bb + rb1 * 128 + (cb ^ ((rb1 & 7) << 4)));
      acc00 = __builtin_amdgcn_mfma_f32_16x16x32_bf16(a0, b0, acc00, 0, 0, 0);
      acc01 = __builtin_amdgcn_mfma_f32_16x16x32_bf16(a0, b1, acc01, 0, 0, 0);
      acc10 = __builtin_amdgcn_mfma_f32_16x16x32_bf16(a1, b0, acc10, 0, 0, 0);
      acc11 = __builtin_amdgcn_mfma_f32_16x16x32_bf16(a1, b1, acc11, 0, 0, 0);
    }
    if (it + 1 < nit) stage((it + 1) & 1);
  }

  #pragma unroll
  for (int am = 0; am < 2; ++am) {
    #pragma unroll
    for (int bn = 0; bn < 2; ++bn) {
      float4v a = am ? (bn ? acc11 : acc10) : (bn ? acc01 : acc00);
      #pragma unroll
      for (int r = 0; r < 4; ++r) {
        const int rowO = m0 + wm + am * 16 + kq * 4 + r;
        const int colO = n0 + wn + bn * 16 + fr;
        float v = a[r];
        if (EPI == EPI_S0) {
          float tv = tanh2(v + bias[colO]);
          f0[(size_t)rowO * 512 + colO] = tv;
          g0[(size_t)rowO * 512 + colO] = f2bf(tv);
        } else { // EPI_EPROJ
          g0[(size_t)rowO * 512 + colO] = f2bf(v + bias[colO]);
        }
      }
    }
  }
}

// -------- k_state: GRU-finish(t-1) -> s_t -> q = 2*(s_t @ Was^T), fused ----------
__global__ __launch_bounds__(512, 1) void k_state(
    const us* __restrict__ xn, const us* __restrict__ Wns, const us* __restrict__ Was,
    const float* __restrict__ zi, const float* __restrict__ npart,
    float* __restrict__ s_f32, us* __restrict__ s_bf,
    float* __restrict__ dec_st_t, float* __restrict__ qbuf, int has_gru) {
  __shared__ alignas(16) char smem[114688];
  char* sL = smem;                  // 64 rows x 1024B swizzled s-tile (bf16, K=512)
  char* As = smem + 65536;          // 2 x 8192
  char* Bs = smem + 81920;          // 2 x 16384
  const int tid = threadIdx.x;
  const int m0 = blockIdx.x * 64;
  const int lane = tid & 63, wv = tid >> 6;
  const int arow = tid >> 3, ac = (tid & 7) * 8;
  const int brow = tid >> 2, bc = (tid & 3) * 16;
  const int wm = (wv >> 2) * 32, wn = (wv & 3) * 32;
  const int fr = lane & 15, kq = lane >> 4;
  const int ra0 = wm + fr, ra1 = ra0 + 16;
  const int rb0 = wn + fr, rb1 = rb0 + 16;

  short8v arv, brv0, brv1;
  auto loadA1 = [&](int k0) {
    arv = *(const short8v*)(xn + (size_t)(m0 + arow) * 512 + k0 + ac);
  };
  auto loadB = [&](const us* W, int n0, int k0) {
    const us* q = W + (size_t)(n0 + brow) * 512 + k0 + bc;
    brv0 = *(const short8v*)q;
    brv1 = *(const short8v*)(q + 8);
  };
  auto stageA = [&](int buf) {
    *(short8v*)(As + buf * 8192 + arow * 128 + ((ac * 2) ^ ((arow & 7) << 4))) = arv;
  };
  auto stageB = [&](int buf) {
    char* bb = Bs + buf * 16384 + brow * 128;
    const int sw = (brow & 7) << 4;
    *(short8v*)(bb + ((bc * 2) ^ sw)) = brv0;
    *(short8v*)(bb + ((bc * 2 + 16) ^ sw)) = brv1;
  };

  if (has_gru) {
    // GEMM1: acc = xn @ Wns^T; epilogue = GRU finish -> s-tile
    for (int nt = 0; nt < 4; ++nt) {
      const int n0 = nt * 128;
      float4v a00 = {0,0,0,0}, a01 = {0,0,0,0}, a10 = {0,0,0,0}, a11 = {0,0,0,0};
      loadA1(0); loadB(Wns, n0, 0);
      stageA(0); stageB(0);
      for (int kt = 0; kt < 8; ++kt) {
        __syncthreads();
        if (kt + 1 < 8) { loadA1((kt + 1) * 64); loadB(Wns, n0, (kt + 1) * 64); }
        const char* ab = As + (kt & 1) * 8192;
        const char* bb = Bs + (kt & 1) * 16384;
        #pragma unroll
        for (int ks = 0; ks < 2; ++ks) {
          const int cb = ks * 64 + kq * 16;
          short8v a0 = *(const short8v*)(ab + ra0 * 128 + (cb ^ ((ra0 & 7) << 4)));
          short8v a1 = *(const short8v*)(ab + ra1 * 128 + (cb ^ ((ra1 & 7) << 4)));
          short8v b0 = *(const short8v*)(bb + rb0 * 128 + (cb ^ ((rb0 & 7) << 4)));
          short8v b1 = *(const short8v*)(bb + rb1 * 128 + (cb ^ ((rb1 & 7) << 4)));
          a00 = __builtin_amdgcn_mfma_f32_16x16x32_bf16(a0, b0, a00, 0, 0, 0);
          a01 = __builtin_amdgcn_mfma_f32_16x16x32_bf16(a0, b1, a01, 0, 0, 0);
          a10 = __builtin_amdgcn_mfma_f32_16x16x32_bf16(a1, b0, a10, 0, 0, 0);
          a11 = __builtin_amdgcn_mfma_f32_16x16x32_bf16(a1, b1, a11, 0, 0, 0);
        }
        if (kt + 1 < 8) { stageA((kt + 1) & 1); stageB((kt + 1) & 1); }
      }
      #pragma unroll
      for (int am = 0; am < 2; ++am) {
        #pragma unroll
        for (int bn = 0; bn < 2; ++bn) {
          float4v a = am ? (bn ? a11 : a10) : (bn ? a01 : a00);
          #pragma unroll
          for (int r = 0; r < 4; ++r) {
            const int lrow = wm + am * 16 + kq * 4 + r;
            const int colG = n0 + wn + bn * 16 + fr;
            const size_t idx = (size_t)(m0 + lrow) * 512 + colG;
            float nv = tanh2(a[r] + npart[idx]);
            float z  = zi[idx];
            float so = s_f32[idx];
            float sn = (1.f - z) * so + z * nv;
            s_f32[idx] = sn;
            us snb = f2bf(sn);
            s_bf[idx] = snb;
            __builtin_nontemporal_store(sn, &dec_st_t[idx]);
            *(us*)(sL + lrow * 1024 + ((2 * colG) ^ ((lrow & 7) << 4))) = snb;
          }
        }
      }
    }
  } else {
    for (int i = tid; i < 64 * 512; i += 512) {
      int r = i >> 9, h2 = i & 511;
      size_t idx = (size_t)(m0 + r) * 512 + h2;
      float v = s_f32[idx];
      *(us*)(sL + r * 1024 + ((2 * h2) ^ ((r & 7) << 4))) = f2bf(v);
      __builtin_nontemporal_store(v, &dec_st_t[idx]);
    }
  }
  __syncthreads();

  // GEMM2: qbuf = 2 * (s @ Was^T), A from sL
  for (int nt = 0; nt < 4; ++nt) {
    const int n0 = nt * 128;
    float4v a00 = {0,0,0,0}, a01 = {0,0,0,0}, a10 = {0,0,0,0}, a11 = {0,0,0,0};
    loadB(Was, n0, 0); stageB(0);
    for (int kt = 0; kt < 8; ++kt) {
      __syncthreads();
      if (kt + 1 < 8) loadB(Was, n0, (kt + 1) * 64);
      const char* bb = Bs + (kt & 1) * 16384;
      #pragma unroll
      for (int ks = 0; ks < 2; ++ks) {
        const int cbA = kt * 128 + ks * 64 + kq * 16;      // byte col in s-tile
        const int cbB = ks * 64 + kq * 16;
        short8v a0 = *(const short8v*)(sL + ra0 * 1024 + (cbA ^ ((ra0 & 7) << 4)));
        short8v a1 = *(const short8v*)(sL + ra1 * 1024 + (cbA ^ ((ra1 & 7) << 4)));
        short8v b0 = *(const short8v*)(bb + rb0 * 128 + (cbB ^ ((rb0 & 7) << 4)));
        short8v b1 = *(const short8v*)(bb + rb1 * 128 + (cbB ^ ((rb1 & 7) << 4)));
        a00 = __builtin_amdgcn_mfma_f32_16x16x32_bf16(a0, b0, a00, 0, 0, 0);
        a01 = __builtin_amdgcn_mfma_f32_16x16x32_bf16(a0, b1, a01, 0, 0, 0);
        a10 = __builtin_amdgcn_mfma_f32_16x16x32_bf16(a1, b0, a10, 0, 0, 0);
        a11 = __builtin_amdgcn_mfma_f32_16x16x32_bf16(a1, b1, a11, 0, 0, 0);
      }
      if (kt + 1 < 8) stageB((kt + 1) & 1);
    }
    #pragma unroll
    for (int am = 0; am < 2; ++am) {
      #pragma unroll
      for (int bn = 0; bn < 2; ++bn) {
        float4v a = am ? (bn ? a11 : a10) : (bn ? a01 : a00);
        #pragma unroll
        for (int r = 0; r < 4; ++r) {
          const int lrow = wm + am * 16 + kq * 4 + r;
          const int colG = n0 + wn + bn * 16 + fr;
          qbuf[(size_t)(m0 + lrow) * 512 + colG] = 2.f * a[r];
        }
      }
    }
    __syncthreads();
  }
}

// -------- k_score: chunk scores + chunk softmax + ci partials (LDS-staged) --------
__global__ __launch_bounds__(256, 2) void k_score(
    const us* __restrict__ ep, const us* __restrict__ src,
    const float* __restrict__ qbuf, const float* __restrict__ vaw,
    const int* __restrict__ slen,
    float* __restrict__ pbuf, float* __restrict__ cpart, float* __restrict__ mlbuf) {
  __shared__ alignas(16) us rows[64][512];       // 64KB staging
  __shared__ float eich[64];
  __shared__ float pch[64];
  __shared__ float wpart[4][512];                // 8KB
  const int bid = blockIdx.x, tid = threadIdx.x;
  const int b = bid >> 2, c = bid & 3;
  const int lane = tid & 63, wv = tid >> 6;      // 4 waves
  const int g0l = lane * 8;
  const int r0 = wv * 16;
  const int len = slen[b];

  // hoisted constants
  float vv2[8]; float sumv = 0.f;
  {
    const float* vp = vaw + g0l;
    #pragma unroll
    for (int j = 0; j < 8; j++) { vv2[j] = 2.f * vp[j]; sumv += vp[j]; }
    #pragma unroll
    for (int off = 32; off > 0; off >>= 1) sumv += __shfl_xor(sumv, off, 64);
  }
  float q2[8];
  {
    const float* qp = qbuf + b * 512 + g0l;
    #pragma unroll
    for (int j = 0; j < 8; j++) q2[j] = qp[j];
  }

  // ---- stage 64 ep rows (1KB each, one gload_lds per row per wave) ----
  {
    const us* gb = ep + ((size_t)b * S_LEN + c * 64 + r0) * NH + lane * 8;
    #pragma unroll
    for (int i = 0; i < 16; ++i)
      gload16(gb + (size_t)i * NH, &rows[r0 + i][0]);
  }
  asm volatile("s_waitcnt vmcnt(0)" ::: "memory");
  __syncthreads();

  // ---- scores on this wave's 16 rows ----
  #pragma unroll
  for (int i = 0; i < 16; ++i) {
    const int r = r0 + i;
    short8v v = *(const short8v*)&rows[r][g0l];
    float acc = 0.f;
    #pragma unroll
    for (int j = 0; j < 8; j++) {
      float arg = __builtin_fmaf(bf2f((us)v[j]), 2.f, q2[j]);
      acc = __builtin_fmaf(vv2[j], __builtin_amdgcn_rcpf(__expf(arg) + 1.f), acc);
    }
    #pragma unroll
    for (int off = 32; off > 0; off >>= 1) acc += __shfl_xor(acc, off, 64);
    if (lane == 0) {
      int sg = c * 64 + r;
      eich[r] = (sg < len) ? (sumv - acc) : -3.0e38f;
    }
  }
  __syncthreads();

  // ---- chunk softmax (wave 0) ----
  if (wv == 0) {
    float e = eich[lane];
    float m = e;
    #pragma unroll
    for (int off = 32; off > 0; off >>= 1) m = fmaxf(m, __shfl_xor(m, off, 64));
    float p = __expf(e - m);
    float l = p;
    #pragma unroll
    for (int off = 32; off > 0; off >>= 1) l += __shfl_xor(l, off, 64);
    pch[lane] = p;
    pbuf[b * 256 + c * 64 + lane] = p;
    if (lane == 0) {
      mlbuf[(b * 4 + c) * 2]     = m;
      mlbuf[(b * 4 + c) * 2 + 1] = l;
    }
  }
  __syncthreads();

  // ---- stage 64 src rows (overwrite) ----
  {
    const us* gb = src + ((size_t)b * S_LEN + c * 64 + r0) * NH + lane * 8;
    #pragma unroll
    for (int i = 0; i < 16; ++i)
      gload16(gb + (size_t)i * NH, &rows[r0 + i][0]);
  }
  asm volatile("s_waitcnt vmcnt(0)" ::: "memory");
  __syncthreads();

  // ---- ci partials ----
  {
    float a8[8] = {0,0,0,0,0,0,0,0};
    #pragma unroll
    for (int i = 0; i < 16; ++i) {
      const int r = r0 + i;
      short8v v = *(const short8v*)&rows[r][g0l];
      float pv = pch[r];
      #pragma unroll
      for (int j = 0; j < 8; j++)
        a8[j] = __builtin_fmaf(pv, bf2f((us)v[j]), a8[j]);
    }
    #pragma unroll
    for (int j = 0; j < 8; j++) wpart[wv][g0l + j] = a8[j];
  }
  __syncthreads();
  #pragma unroll
  for (int rep = 0; rep < 2; rep++) {
    int hh = tid + rep * 256;
    float cp = wpart[0][hh] + wpart[1][hh] + wpart[2][hh] + wpart[3][hh];
    cpart[((size_t)b * 4 + c) * 512 + hh] = cp;
  }
}

// -------- k_combine: merge 4 chunks -> ci, dec_attns[t] --------
__global__ __launch_bounds__(256) void k_combine(
    const float* __restrict__ mlbuf, const float* __restrict__ cpart,
    const float* __restrict__ pbuf,
    us* __restrict__ ci_bf, float* __restrict__ dec_at_t) {
  const int b = blockIdx.x, tid = threadIdx.x;
  float mm[4], ll[4], m = -3.0e38f;
  #pragma unroll
  for (int cc = 0; cc < 4; cc++) {
    mm[cc] = mlbuf[(b * 4 + cc) * 2];
    ll[cc] = mlbuf[(b * 4 + cc) * 2 + 1];
    m = fmaxf(m, mm[cc]);
  }
  float wgt[4], l = 0.f;
  #pragma unroll
  for (int cc = 0; cc < 4; cc++) { wgt[cc] = __expf(mm[cc] - m); l += wgt[cc] * ll[cc]; }
  float invl = __builtin_amdgcn_rcpf(l);
  #pragma unroll
  for (int rep = 0; rep < 2; rep++) {
    int hh = tid + rep * 256;
    float s = wgt[0] * cpart[((size_t)b * 4 + 0) * 512 + hh]
            + wgt[1] * cpart[((size_t)b * 4 + 1) * 512 + hh]
            + wgt[2] * cpart[((size_t)b * 4 + 2) * 512 + hh]
            + wgt[3] * cpart[((size_t)b * 4 + 3) * 512 + hh];
    ci_bf[b * 512 + hh] = f2bf(s * invl);
  }
  float ai = pbuf[b * 256 + tid] * wgt[tid >> 6] * invl;
  __builtin_nontemporal_store(ai, &dec_at_t[b * 256 + tid]);
}

// -------- k_step1: Y = [emb|s|ci] @ W1cat^T + bcat --------
__global__ __launch_bounds__(256, 4) void k_step1(
    const us* __restrict__ emb_t, const us* __restrict__ sbf,
    const us* __restrict__ cibf, const us* __restrict__ W1cat,
    const float* __restrict__ bcat, const float* __restrict__ s_f32,
    float* __restrict__ dec_out_t, float* __restrict__ zi,
    float* __restrict__ npart, us* __restrict__ xn) {
  __shared__ alignas(16) char smem[24576];
  const int bid = blockIdx.x, tid = threadIdx.x;
  const int lane = tid & 63, wv = tid >> 6;
  char* As = smem;            // 64 x 128B
  char* Bs = smem + 8192;     // 128 x 128B
  const int m0 = (bid >> 4) * 64, n0 = (bid & 15) * 128;
  const int fr = lane & 15, kq = lane >> 4;
  const int wm = (wv & 1) * 32, wn0 = (wv >> 1) * 32;
  const int ra0 = wm + fr, ra1 = ra0 + 16;
  float4v acc[2][2][2];
  #pragma unroll
  for (int x = 0; x < 2; x++)
    #pragma unroll
    for (int y = 0; y < 2; y++)
      #pragma unroll
      for (int z = 0; z < 2; z++) acc[x][y][z] = (float4v){0,0,0,0};

  for (int kt = 0; kt < 20; ++kt) {
    __syncthreads();
    #pragma unroll
    for (int j = 0; j < 2; j++) {
      int cid = tid + 256 * j;
      int arow = cid >> 3, ac8 = (cid & 7) * 8;
      int cc = kt * 64 + ac8, rowg = m0 + arow;
      const us* p = (cc < 256) ? emb_t + (size_t)rowg * 256 + cc
                  : (cc < 768) ? sbf + (size_t)rowg * 512 + (cc - 256)
                               : cibf + (size_t)rowg * 512 + (cc - 768);
      *(short8v*)(As + arow * 128 + ((ac8 * 2) ^ ((arow & 7) << 4))) =
          *(const short8v*)p;
    }
    #pragma unroll
    for (int j = 0; j < 4; j++) {
      int cid = tid + 256 * j;
      int brow = cid >> 3, bc8 = (cid & 7) * 8;
      *(short8v*)(Bs + brow * 128 + ((bc8 * 2) ^ ((brow & 7) << 4))) =
          *(const short8v*)(W1cat + (size_t)(n0 + brow) * 1280 + kt * 64 + bc8);
    }
    __syncthreads();
    #pragma unroll
    for (int ks = 0; ks < 2; ++ks) {
      const int cb = ks * 64 + kq * 16;
      short8v a0 = *(const short8v*)(As + ra0 * 128 + (cb ^ ((ra0 & 7) << 4)));
      short8v a1 = *(const short8v*)(As + ra1 * 128 + (cb ^ ((ra1 & 7) << 4)));
      #pragma unroll
      for (int nh = 0; nh < 2; ++nh) {
        const int rb0 = wn0 + nh * 64 + fr, rb1 = rb0 + 16;
        short8v b0 = *(const short8v*)(Bs + rb0 * 128 + (cb ^ ((rb0 & 7) << 4)));
        short8v b1 = *(const short8v*)(Bs + rb1 * 128 + (cb ^ ((rb1 & 7) << 4)));
        acc[nh][0][0] = __builtin_amdgcn_mfma_f32_16x16x32_bf16(a0, b0, acc[nh][0][0], 0, 0, 0);
        acc[nh][0][1] = __builtin_amdgcn_mfma_f32_16x16x32_bf16(a0, b1, acc[nh][0][1], 0, 0, 0);
        acc[nh][1][0] = __builtin_amdgcn_mfma_f32_16x16x32_bf16(a1, b0, acc[nh][1][0], 0, 0, 0);
        acc[nh][1][1] = __builtin_amdgcn_mfma_f32_16x16x32_bf16(a1, b1, acc[nh][1][1], 0, 0, 0);
      }
    }
  }

  #pragma unroll
  for (int nh = 0; nh < 2; ++nh) {
    #pragma unroll
    for (int am = 0; am < 2; ++am) {
      #pragma unroll
      for (int bn = 0; bn < 2; ++bn) {
        #pragma unroll
        for (int r = 0; r < 4; ++r) {
          const int rowO = m0 + wm + am * 16 + kq * 4 + r;
          const int colO = n0 + wn0 + nh * 64 + bn * 16 + fr;
          float v = acc[nh][am][bn][r] + bcat[colO];
          const int qd = colO >> 9, j = colO & 511;
          const size_t idx = (size_t)rowO * 512 + j;
          if      (qd == 0) __builtin_nontemporal_store(v, &dec_out_t[idx]);
          else if (qd == 1) zi[idx] = sigm(v);
          else if (qd == 2) xn[idx] = f2bf(sigm(v) * s_f32[idx]);
          else              npart[idx] = v;
        }
      }
    }
  }
}

} // namespace

extern "C" void kernel_launch(void* const* d_in, const int* in_sizes, int n_in,
                              void* d_out, int out_size, void* d_ws, size_t ws_size,
                              hipStream_t stream) {
  const float* src_enc  = (const float*)d_in[0];
  const int*   tgt      = (const int*)d_in[1];
  const int*   slen     = (const int*)d_in[2];
  const float* emb_tab  = (const float*)d_in[3];
  const float* Wsw      = (const float*)d_in[4];
  const float* Wsb      = (const float*)d_in[5];
  const float* Wzw      = (const float*)d_in[6];
  const float* Wzb      = (const float*)d_in[7];
  const float* Wrw      = (const float*)d_in[8];
  const float* Wrb      = (const float*)d_in[9];
  const float* Wnw      = (const float*)d_in[10];
  const float* Wnb      = (const float*)d_in[11];
  const float* Waw      = (const float*)d_in[12];
  const float* Wab      = (const float*)d_in[13];
  const float* vaw      = (const float*)d_in[14];
  const float* Wow      = (const float*)d_in[15];
  const float* Wob      = (const float*)d_in[16];

  char* ws = (char*)d_ws;
  size_t off = 0;
  auto alloc = [&](size_t bytes) -> void* {
    void* p = ws + off;
    off = (off + bytes + 255) & ~(size_t)255;
    return p;
  };
  us*    src_t  = (us*)alloc(SRC_ELEMS * 2);
  us*    ep_t   = (us*)alloc(SRC_ELEMS * 2);
  us*    emb_bf = (us*)alloc((size_t)NSTEPS * BATCH * NE * 2);
  us*    W1cat  = (us*)alloc((size_t)N1 * 1280 * 2);
  us*    Wns    = (us*)alloc((size_t)512 * 512 * 2);
  us*    Was    = (us*)alloc((size_t)512 * 512 * 2);
  us*    Wae    = (us*)alloc((size_t)512 * 512 * 2);
  us*    Wsbf   = (us*)alloc((size_t)512 * 512 * 2);
  float* bcat   = (float*)alloc((size_t)N1 * 4);
  float* s_f32  = (float*)alloc((size_t)BATCH * NH * 4);
  us*    s_bf   = (us*)alloc((size_t)BATCH * NH * 2);
  float* qbuf   = (float*)alloc((size_t)BATCH * NH * 4);
  float* zi     = (float*)alloc((size_t)BATCH * NH * 4);
  float* npart  = (float*)alloc((size_t)BATCH * NH * 4);
  us*    xn_bf  = (us*)alloc((size_t)BATCH * NH * 2);
  us*    ci_bf  = (us*)alloc((size_t)BATCH * NH * 2);
  float* pbuf   = (float*)alloc((size_t)BATCH * S_LEN * 4);
  float* cpart  = (float*)alloc((size_t)BATCH * 4 * NH * 4);
  float* mlbuf  = (float*)alloc((size_t)BATCH * 4 * 2 * 4);

  float* out         = (float*)d_out;
  float* dec_outputs = out;
  float* dec_states  = out + (size_t)NSTEPS * BATCH * NH;
  float* dec_attns   = dec_states + (size_t)NSTEPS * BATCH * NH;

  // ---- prologue ----
  k_conv_src<<<4096, 256, 0, stream>>>(src_enc, src_t);
  k_conv_w<<<2048, 256, 0, stream>>>(Wow, Wzw, Wrw, Wnw, Waw, Wsw,
                                     Wob, Wzb, Wrb, Wnb,
                                     W1cat, Wns, Was, Wae, Wsbf, bcat);
  k_emb<<<2048, 256, 0, stream>>>(tgt, emb_tab, emb_bf);
  // s0 = tanh(src_enc[0] @ Ws^T + Ws_b): src_t rows (b, s=0) at stride S*NH
  k_gemm<EPI_S0><<<dim3(4, 4), 512, 0, stream>>>(
      src_t, S_LEN * NH, Wsbf, 512, 512, Wsb, s_f32, s_bf);
  // ep_t[b,s] = src_t[b,s] @ Wae^T + Wa_b
  k_gemm<EPI_EPROJ><<<dim3(1024, 4), 512, 0, stream>>>(
      src_t, 512, Wae, 512, 512, Wab, nullptr, ep_t);

  // ---- 127 steps x 4 stream-ordered kernels ----
  for (int t = 0; t < NSTEPS; t++) {
    k_state<<<4, 512, 0, stream>>>(
        xn_bf, Wns, Was, zi, npart, s_f32, s_bf,
        dec_states + (size_t)t * BATCH * NH, qbuf, t > 0 ? 1 : 0);
    k_score<<<1024, 256, 0, stream>>>(
        ep_t, src_t, qbuf, vaw, slen, pbuf, cpart, mlbuf);
    k_combine<<<256, 256, 0, stream>>>(
        mlbuf, cpart, pbuf, ci_bf, dec_attns + (size_t)t * BATCH * S_LEN);
    k_step1<<<64, 256, 0, stream>>>(
        emb_bf + (size_t)t * BATCH * NE, s_bf, ci_bf, W1cat, bcat, s_f32,
        dec_outputs + (size_t)t * BATCH * NH, zi, npart, xn_bf);
  }
}

// Round 7
// 11154.836 us; speedup vs baseline: 7.2203x; 1.2742x over previous
//
#include <hip/hip_runtime.h>
#include <hip/hip_bf16.h>
#include <cstdint>
#include <cstddef>

namespace {

constexpr int S_LEN  = 256;
constexpr int BATCH  = 256;
constexpr int NH     = 512;
constexpr int NE     = 256;
constexpr int NSTEPS = 127;          // TGT_LEN-1
constexpr int N1     = 2048;         // [Wo;Wz;Wr;Wn_partial]
constexpr size_t SB        = (size_t)S_LEN * BATCH;   // 65536
constexpr size_t SRC_ELEMS = SB * NH;                 // 33,554,432

typedef __attribute__((ext_vector_type(8))) short  short8v;
typedef __attribute__((ext_vector_type(4))) float  float4v;
typedef unsigned short us;

constexpr int EPI_EPROJ = 1, EPI_S0 = 4;

__device__ __forceinline__ float bf2f(us u) {
  union { unsigned int i; float f; } c; c.i = ((unsigned int)u) << 16; return c.f;
}
__device__ __forceinline__ us f2bf(float f) {
  union { float f; unsigned int i; } c; c.f = f;
  unsigned int x = c.i;
  return (us)((x + 0x7FFFu + ((x >> 16) & 1u)) >> 16);
}
// tanh(x) = 1 - 2/(e^{2x}+1)
__device__ __forceinline__ float tanh2(float x) {
  return 1.f - 2.f * __builtin_amdgcn_rcpf(__expf(2.f * x) + 1.f);
}
__device__ __forceinline__ float sigm(float x) {
  return __builtin_amdgcn_rcpf(1.f + __expf(-x));
}
// one wave stages 1KB: per-lane global addr g (lane*16B apart), uniform LDS dst l
__device__ __forceinline__ void gload16(const us* g, us* l) {
  __builtin_amdgcn_global_load_lds(
      (const __attribute__((address_space(1))) unsigned int*)g,
      (__attribute__((address_space(3))) unsigned int*)l, 16, 0, 0);
}

// ---------------- prologue: conversions ----------------

// src_enc (S,B,H) f32 -> src_t (B,S,H) bf16
__global__ void k_conv_src(const float* __restrict__ src, us* __restrict__ dst) {
  const int total = S_LEN * BATCH * 64;       // 8-elem chunks, dest-linear
  int i = blockIdx.x * blockDim.x + threadIdx.x;
  int stride = gridDim.x * blockDim.x;
  for (; i < total; i += stride) {
    int c = i & 63, s = (i >> 6) & 255, b = i >> 14;
    const float* p = src + ((size_t)s * BATCH + b) * NH + c * 8;
    float4 v0 = *(const float4*)p;
    float4 v1 = *(const float4*)(p + 4);
    us o[8] = { f2bf(v0.x), f2bf(v0.y), f2bf(v0.z), f2bf(v0.w),
                f2bf(v1.x), f2bf(v1.y), f2bf(v1.z), f2bf(v1.w) };
    *(short8v*)(dst + (size_t)i * 8) = *(const short8v*)o;
  }
}

__global__ void k_conv_w(const float* __restrict__ Wo, const float* __restrict__ Wz,
                         const float* __restrict__ Wr, const float* __restrict__ Wn,
                         const float* __restrict__ Wa, const float* __restrict__ Ws,
                         const float* __restrict__ Wob, const float* __restrict__ Wzb,
                         const float* __restrict__ Wrb, const float* __restrict__ Wnb,
                         us* __restrict__ W1cat, us* __restrict__ Wns,
                         us* __restrict__ Was, us* __restrict__ Wae,
                         us* __restrict__ Wsbf, float* __restrict__ bcat) {
  const int T1 = 2048 * 1280;
  const int T2 = 512 * 512;
  const int total = T1 + 4 * T2 + 2048;
  int i = blockIdx.x * blockDim.x + threadIdx.x;
  int stride = gridDim.x * blockDim.x;
  for (; i < total; i += stride) {
    int idx = i;
    if (idx < T1) {
      int row = idx / 1280, col = idx - row * 1280;
      float v;
      if      (row < 512)  v = Wo[row * 1280 + col];
      else if (row < 1024) v = Wz[(row - 512) * 1280 + col];
      else if (row < 1536) v = Wr[(row - 1024) * 1280 + col];
      else {
        int g = row - 1536;
        v = (col >= 256 && col < 768) ? 0.f : Wn[g * 1280 + col];
      }
      W1cat[idx] = f2bf(v);
    } else if ((idx -= T1) < T2) {
      int g = idx >> 9, j = idx & 511;
      Wns[idx] = f2bf(Wn[g * 1280 + 256 + j]);
    } else if ((idx -= T2) < T2) {
      int g = idx >> 9, h = idx & 511;
      Was[idx] = f2bf(Wa[g * 1024 + h]);
    } else if ((idx -= T2) < T2) {
      int g = idx >> 9, h = idx & 511;
      Wae[idx] = f2bf(Wa[g * 1024 + 512 + h]);
    } else if ((idx -= T2) < T2) {
      Wsbf[idx] = f2bf(Ws[idx]);
    } else {
      idx -= T2;
      bcat[idx] = (idx < 512) ? Wob[idx]
                : (idx < 1024) ? Wzb[idx - 512]
                : (idx < 1536) ? Wrb[idx - 1024]
                               : Wnb[idx - 1536];
    }
  }
}

__global__ void k_emb(const int* __restrict__ tgt, const float* __restrict__ table,
                      us* __restrict__ emb) {
  const int total = NSTEPS * BATCH * NE;
  int i = blockIdx.x * blockDim.x + threadIdx.x;
  int stride = gridDim.x * blockDim.x;
  for (; i < total; i += stride) {
    int e  = i & (NE - 1);
    int tb = i >> 8;
    int sym = tgt[tb];
    emb[i] = f2bf(table[sym * NE + e]);
  }
}

// ------------- prologue 8-wave MFMA GEMM tile: 64x128, BK=64 (s0 / eproj) ----------
template<int EPI>
__global__ __launch_bounds__(512, 2) void k_gemm(
    const us* __restrict__ A0, int lda, const us* __restrict__ Bw, int ldb, int K,
    const float* __restrict__ bias, float* __restrict__ f0, us* __restrict__ g0) {
  __shared__ alignas(16) char smem[49152];
  char* As0 = smem;               // 2 x 8192
  char* Bs0 = smem + 16384;       // 2 x 16384
  const int tid = threadIdx.x;
  const int m0 = blockIdx.x * 64, n0 = blockIdx.y * 128;
  const int arow = tid >> 3, ac = (tid & 7) * 8;
  const int brow = tid >> 2, bc = (tid & 3) * 16;
  short8v ar, br0, br1;

  auto loadT = [&](int k0) {
    ar = *(const short8v*)(A0 + (size_t)(m0 + arow) * lda + (k0 + ac));
    const us* q = Bw + (size_t)(n0 + brow) * ldb + (k0 + bc);
    br0 = *(const short8v*)q;
    br1 = *(const short8v*)(q + 8);
  };
  auto stage = [&](int buf) {
    *(short8v*)(As0 + buf * 8192 + arow * 128 + ((ac * 2) ^ ((arow & 7) << 4))) = ar;
    char* bb = Bs0 + buf * 16384 + brow * 128;
    const int sw = (brow & 7) << 4;
    *(short8v*)(bb + ((bc * 2) ^ sw)) = br0;
    *(short8v*)(bb + ((bc * 2 + 16) ^ sw)) = br1;
  };

  const int lane = tid & 63, wave = tid >> 6;
  const int wm = (wave >> 2) * 32, wn = (wave & 3) * 32;
  const int fr = lane & 15, kq = lane >> 4;
  const int ra0 = wm + fr, ra1 = ra0 + 16;
  const int rb0 = wn + fr, rb1 = rb0 + 16;
  float4v acc00 = {0,0,0,0}, acc01 = {0,0,0,0}, acc10 = {0,0,0,0}, acc11 = {0,0,0,0};

  loadT(0);
  stage(0);
  const int nit = K >> 6;
  for (int it = 0; it < nit; ++it) {
    __syncthreads();
    if (it + 1 < nit) loadT((it + 1) << 6);
    const char* ab = As0 + (it & 1) * 8192;
    const char* bb = Bs0 + (it & 1) * 16384;
    #pragma unroll
    for (int ks = 0; ks < 2; ++ks) {
      const int cb = ks * 64 + kq * 16;
      short8v a0 = *(const short8v*)(ab + ra0 * 128 + (cb ^ ((ra0 & 7) << 4)));
      short8v a1 = *(const short8v*)(ab + ra1 * 128 + (cb ^ ((ra1 & 7) << 4)));
      short8v b0 = *(const short8v*)(bb + rb0 * 128 + (cb ^ ((rb0 & 7) << 4)));
      short8v b1 = *(const short8v*)(bb + rb1 * 128 + (cb ^ ((rb1 & 7) << 4)));
      acc00 = __builtin_amdgcn_mfma_f32_16x16x32_bf16(a0, b0, acc00, 0, 0, 0);
      acc01 = __builtin_amdgcn_mfma_f32_16x16x32_bf16(a0, b1, acc01, 0, 0, 0);
      acc10 = __builtin_amdgcn_mfma_f32_16x16x32_bf16(a1, b0, acc10, 0, 0, 0);
      acc11 = __builtin_amdgcn_mfma_f32_16x16x32_bf16(a1, b1, acc11, 0, 0, 0);
    }
    if (it + 1 < nit) stage((it + 1) & 1);
  }

  #pragma unroll
  for (int am = 0; am < 2; ++am) {
    #pragma unroll
    for (int bn = 0; bn < 2; ++bn) {
      float4v a = am ? (bn ? acc11 : acc10) : (bn ? acc01 : acc00);
      #pragma unroll
      for (int r = 0; r < 4; ++r) {
        const int rowO = m0 + wm + am * 16 + kq * 4 + r;
        const int colO = n0 + wn + bn * 16 + fr;
        float v = a[r];
        if (EPI == EPI_S0) {
          float tv = tanh2(v + bias[colO]);
          f0[(size_t)rowO * 512 + colO] = tv;
          g0[(size_t)rowO * 512 + colO] = f2bf(tv);
        } else { // EPI_EPROJ
          g0[(size_t)rowO * 512 + colO] = f2bf(v + bias[colO]);
        }
      }
    }
  }
}

// ---- k_fused: GRU-finish + q + scores + softmax(max-free) + ci, per batch b ----
__global__ __launch_bounds__(512, 1) void k_fused(
    const us* __restrict__ ep,        // (B,S,H) bf16
    const us* __restrict__ src,       // (B,S,H) bf16
    const us* __restrict__ Wns, const us* __restrict__ Was,
    const float* __restrict__ vaw, const int* __restrict__ slen,
    const float* __restrict__ zi, const float* __restrict__ npart,
    const us* __restrict__ xn,
    float* __restrict__ s_f32, us* __restrict__ s_bf, us* __restrict__ ci_bf,
    float* __restrict__ dec_st_t, float* __restrict__ dec_at_t, int has_gru) {
  __shared__ alignas(16) us stg[3][32][512];   // 96KB, 3-deep stream buffers
  __shared__ float sfl[512];
  __shared__ float q2l[512];
  __shared__ float pl[256];
  __shared__ float lred[8];
  __shared__ float wpart[8][512];              // 16KB (row 0 reused as xnf)
  const int b = blockIdx.x, tid = threadIdx.x;
  const int lane = tid & 63, wv = tid >> 6;    // 8 waves
  const int g0l = lane * 8;
  const int len = slen[b];
  const us* epb  = ep  + (size_t)b * S_LEN * NH;
  const us* srcb = src + (size_t)b * S_LEN * NH;

  // hoisted attention constants
  float vv2[8]; float sumv = 0.f;
  {
    const float* vp = vaw + g0l;
    #pragma unroll
    for (int j = 0; j < 8; j++) { vv2[j] = 2.f * vp[j]; sumv += vp[j]; }
    #pragma unroll
    for (int off = 32; off > 0; off >>= 1) sumv += __shfl_xor(sumv, off, 64);
  }

  // prefetch: 3 chunks (32 rows each) — wave wv owns rows wv*4..wv*4+3
  auto issue3 = [&](const us* base) {
    #pragma unroll
    for (int c = 0; c < 3; ++c)
      #pragma unroll
      for (int i = 0; i < 4; ++i) {
        int r = wv * 4 + i;
        gload16(base + (size_t)(c * 32 + r) * NH + g0l, &stg[c][r][0]);
      }
  };

  // ---- B: GRU finish of step t-1 -> s_t ; dec_states[t] ----
  float s_new;
  if (has_gru) {
    float* xnf = &wpart[0][0];
    xnf[tid] = bf2f(xn[b * 512 + tid]);
    __syncthreads();
    issue3(epb);               // ep prefetch hides under the matvec below
    const us* wr = Wns + (size_t)tid * 512;
    float acc = 0.f;
    #pragma unroll 8
    for (int k = 0; k < 64; ++k) {
      short8v w8 = ((const short8v*)wr)[k];
      #pragma unroll
      for (int j = 0; j < 8; j++)
        acc = __builtin_fmaf(bf2f((us)w8[j]), xnf[k * 8 + j], acc);
    }
    float z  = zi[b * 512 + tid];
    float so = s_f32[b * 512 + tid];
    float nv = tanh2(npart[b * 512 + tid] + acc);
    s_new = (1.f - z) * so + z * nv;
    s_f32[b * 512 + tid] = s_new;
    s_bf[b * 512 + tid]  = f2bf(s_new);
  } else {
    issue3(epb);
    s_new = s_f32[b * 512 + tid];
  }
  sfl[tid] = s_new;
  __builtin_nontemporal_store(s_new, &dec_st_t[b * 512 + tid]);
  __syncthreads();

  // ---- C: q = 2 * (s_t @ Was^T) ----
  {
    const us* wr = Was + (size_t)tid * 512;
    float acc = 0.f;
    #pragma unroll 8
    for (int k = 0; k < 64; ++k) {
      short8v w8 = ((const short8v*)wr)[k];
      #pragma unroll
      for (int j = 0; j < 8; j++)
        acc = __builtin_fmaf(bf2f((us)w8[j]), sfl[k * 8 + j], acc);
    }
    q2l[tid] = 2.f * acc;
  }
  __syncthreads();

  // ---- D: scores + exp (max-free: |ei| <= sum|va| ~ 20, f32-safe) ----
  float q2[8];
  #pragma unroll
  for (int j = 0; j < 8; j++) q2[j] = q2l[g0l + j];
  float lsum = 0.f;
  #pragma unroll
  for (int c = 0; c < 8; ++c) {
    if (c < 6)      asm volatile("s_waitcnt vmcnt(8)" ::: "memory");
    else if (c == 6) asm volatile("s_waitcnt vmcnt(4)" ::: "memory");
    else             asm volatile("s_waitcnt vmcnt(0)" ::: "memory");
    #pragma unroll
    for (int i = 0; i < 4; ++i) {
      const int r = wv * 4 + i;
      const int s = c * 32 + r;
      short8v v = *(const short8v*)&stg[c % 3][r][g0l];
      float acc = 0.f;
      #pragma unroll
      for (int j = 0; j < 8; j++) {
        float arg = __builtin_fmaf(bf2f((us)v[j]), 2.f, q2[j]);
        acc = __builtin_fmaf(vv2[j], __builtin_amdgcn_rcpf(__expf(arg) + 1.f), acc);
      }
      #pragma unroll
      for (int off = 32; off > 0; off >>= 1) acc += __shfl_xor(acc, off, 64);
      float p = (s < len) ? __expf(sumv - acc) : 0.f;
      if (lane == 0) pl[s] = p;
      lsum += p;
    }
    // ensure ds_reads of this buffer completed before refilling it
    asm volatile("s_waitcnt lgkmcnt(0)" ::: "memory");
    __builtin_amdgcn_sched_barrier(0);
    if (c + 3 < 8) {
      #pragma unroll
      for (int i = 0; i < 4; ++i) {
        const int r = wv * 4 + i;
        gload16(epb + (size_t)((c + 3) * 32 + r) * NH + g0l, &stg[(c + 3) % 3][r][0]);
      }
    }
  }
  if (lane == 0) lred[wv] = lsum;
  __syncthreads();
  float l = 0.f;
  #pragma unroll
  for (int w = 0; w < 8; w++) l += lred[w];
  const float inv = __builtin_amdgcn_rcpf(l);

  // ---- E: attention weights out; prefetch src ----
  if (tid < 256)
    __builtin_nontemporal_store(pl[tid] * inv, &dec_at_t[b * 256 + tid]);
  issue3(srcb);

  // ---- F: ci = (sum_s p[s]*src[b,s,:]) * inv ----
  float a8[8] = {0,0,0,0,0,0,0,0};
  #pragma unroll
  for (int c = 0; c < 8; ++c) {
    if (c < 6)      asm volatile("s_waitcnt vmcnt(8)" ::: "memory");
    else if (c == 6) asm volatile("s_waitcnt vmcnt(4)" ::: "memory");
    else             asm volatile("s_waitcnt vmcnt(0)" ::: "memory");
    #pragma unroll
    for (int i = 0; i < 4; ++i) {
      const int r = wv * 4 + i;
      const int s = c * 32 + r;
      short8v v = *(const short8v*)&stg[c % 3][r][g0l];
      float pv = pl[s];
      #pragma unroll
      for (int j = 0; j < 8; j++)
        a8[j] = __builtin_fmaf(pv, bf2f((us)v[j]), a8[j]);
    }
    asm volatile("s_waitcnt lgkmcnt(0)" ::: "memory");
    __builtin_amdgcn_sched_barrier(0);
    if (c + 3 < 8) {
      #pragma unroll
      for (int i = 0; i < 4; ++i) {
        const int r = wv * 4 + i;
        gload16(srcb + (size_t)((c + 3) * 32 + r) * NH + g0l, &stg[(c + 3) % 3][r][0]);
      }
    }
  }
  #pragma unroll
  for (int j = 0; j < 8; j++) wpart[wv][g0l + j] = a8[j];
  __syncthreads();
  float cv = 0.f;
  #pragma unroll
  for (int w = 0; w < 8; w++) cv += wpart[w][tid];
  ci_bf[b * 512 + tid] = f2bf(cv * inv);
}

// -------- k_step1: Y = [emb|s|ci] @ W1cat^T + bcat --------
__global__ __launch_bounds__(256, 4) void k_step1(
    const us* __restrict__ emb_t, const us* __restrict__ sbf,
    const us* __restrict__ cibf, const us* __restrict__ W1cat,
    const float* __restrict__ bcat, const float* __restrict__ s_f32,
    float* __restrict__ dec_out_t, float* __restrict__ zi,
    float* __restrict__ npart, us* __restrict__ xn) {
  __shared__ alignas(16) char smem[24576];
  const int bid = blockIdx.x, tid = threadIdx.x;
  const int lane = tid & 63, wv = tid >> 6;
  char* As = smem;            // 64 x 128B
  char* Bs = smem + 8192;     // 128 x 128B
  const int m0 = (bid >> 4) * 64, n0 = (bid & 15) * 128;
  const int fr = lane & 15, kq = lane >> 4;
  const int wm = (wv & 1) * 32, wn0 = (wv >> 1) * 32;
  const int ra0 = wm + fr, ra1 = ra0 + 16;
  float4v acc[2][2][2];
  #pragma unroll
  for (int x = 0; x < 2; x++)
    #pragma unroll
    for (int y = 0; y < 2; y++)
      #pragma unroll
      for (int z = 0; z < 2; z++) acc[x][y][z] = (float4v){0,0,0,0};

  for (int kt = 0; kt < 20; ++kt) {
    __syncthreads();
    #pragma unroll
    for (int j = 0; j < 2; j++) {
      int cid = tid + 256 * j;
      int arow = cid >> 3, ac8 = (cid & 7) * 8;
      int cc = kt * 64 + ac8, rowg = m0 + arow;
      const us* p = (cc < 256) ? emb_t + (size_t)rowg * 256 + cc
                  : (cc < 768) ? sbf + (size_t)rowg * 512 + (cc - 256)
                               : cibf + (size_t)rowg * 512 + (cc - 768);
      *(short8v*)(As + arow * 128 + ((ac8 * 2) ^ ((arow & 7) << 4))) =
          *(const short8v*)p;
    }
    #pragma unroll
    for (int j = 0; j < 4; j++) {
      int cid = tid + 256 * j;
      int brow = cid >> 3, bc8 = (cid & 7) * 8;
      *(short8v*)(Bs + brow * 128 + ((bc8 * 2) ^ ((brow & 7) << 4))) =
          *(const short8v*)(W1cat + (size_t)(n0 + brow) * 1280 + kt * 64 + bc8);
    }
    __syncthreads();
    #pragma unroll
    for (int ks = 0; ks < 2; ++ks) {
      const int cb = ks * 64 + kq * 16;
      short8v a0 = *(const short8v*)(As + ra0 * 128 + (cb ^ ((ra0 & 7) << 4)));
      short8v a1 = *(const short8v*)(As + ra1 * 128 + (cb ^ ((ra1 & 7) << 4)));
      #pragma unroll
      for (int nh = 0; nh < 2; ++nh) {
        const int rb0 = wn0 + nh * 64 + fr, rb1 = rb0 + 16;
        short8v b0 = *(const short8v*)(Bs + rb0 * 128 + (cb ^ ((rb0 & 7) << 4)));
        short8v b1 = *(const short8v*)(Bs + rb1 * 128 + (cb ^ ((rb1 & 7) << 4)));
        acc[nh][0][0] = __builtin_amdgcn_mfma_f32_16x16x32_bf16(a0, b0, acc[nh][0][0], 0, 0, 0);
        acc[nh][0][1] = __builtin_amdgcn_mfma_f32_16x16x32_bf16(a0, b1, acc[nh][0][1], 0, 0, 0);
        acc[nh][1][0] = __builtin_amdgcn_mfma_f32_16x16x32_bf16(a1, b0, acc[nh][1][0], 0, 0, 0);
        acc[nh][1][1] = __builtin_amdgcn_mfma_f32_16x16x32_bf16(a1, b1, acc[nh][1][1], 0, 0, 0);
      }
    }
  }

  #pragma unroll
  for (int nh = 0; nh < 2; ++nh) {
    #pragma unroll
    for (int am = 0; am < 2; ++am) {
      #pragma unroll
      for (int bn = 0; bn < 2; ++bn) {
        #pragma unroll
        for (int r = 0; r < 4; ++r) {
          const int rowO = m0 + wm + am * 16 + kq * 4 + r;
          const int colO = n0 + wn0 + nh * 64 + bn * 16 + fr;
          float v = acc[nh][am][bn][r] + bcat[colO];
          const int qd = colO >> 9, j = colO & 511;
          const size_t idx = (size_t)rowO * 512 + j;
          if      (qd == 0) __builtin_nontemporal_store(v, &dec_out_t[idx]);
          else if (qd == 1) zi[idx] = sigm(v);
          else if (qd == 2) xn[idx] = f2bf(sigm(v) * s_f32[idx]);
          else              npart[idx] = v;
        }
      }
    }
  }
}

} // namespace

extern "C" void kernel_launch(void* const* d_in, const int* in_sizes, int n_in,
                              void* d_out, int out_size, void* d_ws, size_t ws_size,
                              hipStream_t stream) {
  const float* src_enc  = (const float*)d_in[0];
  const int*   tgt      = (const int*)d_in[1];
  const int*   slen     = (const int*)d_in[2];
  const float* emb_tab  = (const float*)d_in[3];
  const float* Wsw      = (const float*)d_in[4];
  const float* Wsb      = (const float*)d_in[5];
  const float* Wzw      = (const float*)d_in[6];
  const float* Wzb      = (const float*)d_in[7];
  const float* Wrw      = (const float*)d_in[8];
  const float* Wrb      = (const float*)d_in[9];
  const float* Wnw      = (const float*)d_in[10];
  const float* Wnb      = (const float*)d_in[11];
  const float* Waw      = (const float*)d_in[12];
  const float* Wab      = (const float*)d_in[13];
  const float* vaw      = (const float*)d_in[14];
  const float* Wow      = (const float*)d_in[15];
  const float* Wob      = (const float*)d_in[16];

  char* ws = (char*)d_ws;
  size_t off = 0;
  auto alloc = [&](size_t bytes) -> void* {
    void* p = ws + off;
    off = (off + bytes + 255) & ~(size_t)255;
    return p;
  };
  us*    src_t  = (us*)alloc(SRC_ELEMS * 2);
  us*    ep_t   = (us*)alloc(SRC_ELEMS * 2);
  us*    emb_bf = (us*)alloc((size_t)NSTEPS * BATCH * NE * 2);
  us*    W1cat  = (us*)alloc((size_t)N1 * 1280 * 2);
  us*    Wns    = (us*)alloc((size_t)512 * 512 * 2);
  us*    Was    = (us*)alloc((size_t)512 * 512 * 2);
  us*    Wae    = (us*)alloc((size_t)512 * 512 * 2);
  us*    Wsbf   = (us*)alloc((size_t)512 * 512 * 2);
  float* bcat   = (float*)alloc((size_t)N1 * 4);
  float* s_f32  = (float*)alloc((size_t)BATCH * NH * 4);
  us*    s_bf   = (us*)alloc((size_t)BATCH * NH * 2);
  float* zi     = (float*)alloc((size_t)BATCH * NH * 4);
  float* npart  = (float*)alloc((size_t)BATCH * NH * 4);
  us*    xn_bf  = (us*)alloc((size_t)BATCH * NH * 2);
  us*    ci_bf  = (us*)alloc((size_t)BATCH * NH * 2);

  float* out         = (float*)d_out;
  float* dec_outputs = out;
  float* dec_states  = out + (size_t)NSTEPS * BATCH * NH;
  float* dec_attns   = dec_states + (size_t)NSTEPS * BATCH * NH;

  // ---- prologue ----
  k_conv_src<<<4096, 256, 0, stream>>>(src_enc, src_t);
  k_conv_w<<<2048, 256, 0, stream>>>(Wow, Wzw, Wrw, Wnw, Waw, Wsw,
                                     Wob, Wzb, Wrb, Wnb,
                                     W1cat, Wns, Was, Wae, Wsbf, bcat);
  k_emb<<<2048, 256, 0, stream>>>(tgt, emb_tab, emb_bf);
  // s0 = tanh(src_enc[0] @ Ws^T + Ws_b): src_t rows (b, s=0) at stride S*NH
  k_gemm<EPI_S0><<<dim3(4, 4), 512, 0, stream>>>(
      src_t, S_LEN * NH, Wsbf, 512, 512, Wsb, s_f32, s_bf);
  // ep_t[b,s] = src_t[b,s] @ Wae^T + Wa_b
  k_gemm<EPI_EPROJ><<<dim3(1024, 4), 512, 0, stream>>>(
      src_t, 512, Wae, 512, 512, Wab, nullptr, ep_t);

  // ---- 127 steps x 2 kernels ----
  for (int t = 0; t < NSTEPS; t++) {
    k_fused<<<BATCH, 512, 0, stream>>>(
        ep_t, src_t, Wns, Was, vaw, slen, zi, npart, xn_bf,
        s_f32, s_bf, ci_bf,
        dec_states + (size_t)t * BATCH * NH,
        dec_attns + (size_t)t * BATCH * S_LEN, t > 0 ? 1 : 0);
    k_step1<<<64, 256, 0, stream>>>(
        emb_bf + (size_t)t * BATCH * NE, s_bf, ci_bf, W1cat, bcat, s_f32,
        dec_outputs + (size_t)t * BATCH * NH, zi, npart, xn_bf);
  }
}